// Round 1
// 908.003 us; speedup vs baseline: 1.6118x; 1.6118x over previous
//
#include <hip/hip_runtime.h>
#include <math.h>

// Problem constants
#define MROWS 2048      // BN*SN = 32*64
#define NCOLS 256       // NDF
#define KDIM  65536     // IN_DIM
#define NCLU  100

// ---- legacy (fallback) GEMM config ----
#define BM 128
#define BN 128
#define BK 32
#define SPLITK 16
#define KCHUNK (KDIM / SPLITK)   // 4096
#define SA 132
#define SB 128

// ---- MFMA GEMM config ----
#define BMT 128
#define BNT 128
#define BKT 32
#define LDT 40    // padded f16 LDS stride (+8 halves = +16B: 2-way-max bank aliasing)

typedef _Float16 half8  __attribute__((ext_vector_type(8)));
typedef _Float16 half4v __attribute__((ext_vector_type(4)));
typedef float    f32x4  __attribute__((ext_vector_type(4)));

// ------------------------------------------------------------------
// Prepass: B [K=65536][N=256] fp32  ->  Bt_hi/Bt_lo [N=256][K=65536] f16
// (transpose so MFMA B-fragments are k-contiguous, + hi/lo split so
//  a_h*(b_h+b_l) = a_h*b exactly; only A's f16 rounding remains)
// ------------------------------------------------------------------
__global__ __launch_bounds__(256, 4)
void prep_b_kernel(const float* __restrict__ B,
                   _Float16* __restrict__ Bth, _Float16* __restrict__ Btl)
{
    __shared__ float T[64][65];   // +1 pad: conflict-free column reads
    const int t  = threadIdx.x;
    const int k0 = blockIdx.x * 64;
    const int n0 = blockIdx.y * 64;

    {
        const int kl = t >> 4;          // 0..15
        const int n4 = (t & 15) * 4;    // 0..60
        #pragma unroll
        for (int i = 0; i < 4; ++i) {
            const float4 v = *(const float4*)(B + (size_t)(k0 + kl + 16 * i) * NCOLS + n0 + n4);
            T[kl + 16 * i][n4 + 0] = v.x;
            T[kl + 16 * i][n4 + 1] = v.y;
            T[kl + 16 * i][n4 + 2] = v.z;
            T[kl + 16 * i][n4 + 3] = v.w;
        }
    }
    __syncthreads();
    {
        const int nl = t >> 2;          // 0..63
        const int kc = (t & 3) * 16;    // 0,16,32,48
        half8 h0, h1, l0, l1;
        #pragma unroll
        for (int j = 0; j < 8; ++j) {
            float v = T[kc + j][nl];
            _Float16 h = (_Float16)v;
            h0[j] = h; l0[j] = (_Float16)(v - (float)h);
            v = T[kc + 8 + j][nl];
            h = (_Float16)v;
            h1[j] = h; l1[j] = (_Float16)(v - (float)h);
        }
        const size_t off = (size_t)(n0 + nl) * KDIM + k0 + kc;
        *(half8*)(Bth + off)     = h0;
        *(half8*)(Bth + off + 8) = h1;
        *(half8*)(Btl + off)     = l0;
        *(half8*)(Btl + off + 8) = l1;
    }
}

// ------------------------------------------------------------------
// MFMA split-K GEMM: C += A(f32->f16 rounded) @ (Bh + Bl)
// grid (16, 2, 16), 256 thr = 4 waves in 2x2; per-wave 64x64 output.
// fp32 atomics into pre-zeroed C (same epilogue as verified baseline).
// ------------------------------------------------------------------
__global__ __launch_bounds__(256, 1)
void gemm_mfma_kernel(const float* __restrict__ A,
                      const _Float16* __restrict__ Bth,
                      const _Float16* __restrict__ Btl,
                      float* __restrict__ C)
{
    __shared__ _Float16 As [BMT][LDT];
    __shared__ _Float16 Bhs[BNT][LDT];
    __shared__ _Float16 Bls[BNT][LDT];

    const int t    = threadIdx.x;
    const int lane = t & 63;
    const int wid  = t >> 6;
    const int wm   = wid >> 1;      // 0..1
    const int wn   = wid & 1;       // 0..1

    const int bm = blockIdx.x;
    const int bn = blockIdx.y;
    const int ks = blockIdx.z;

    const float*    Ab  = A   + (size_t)bm * BMT * KDIM + (size_t)ks * KCHUNK;
    const _Float16* Bhb = Bth + (size_t)bn * BNT * KDIM + (size_t)ks * KCHUNK;
    const _Float16* Blb = Btl + (size_t)bn * BNT * KDIM + (size_t)ks * KCHUNK;

    // staging decomposition
    const int am  = t >> 3;         // A row 0..31 (+32/rep), 8 lanes/row -> coalesced
    const int ak  = (t & 7) * 4;    // A float4 col
    const int bnr = t >> 2;         // B row 0..63 (+64/rep)
    const int bk  = (t & 3) * 8;    // B f16 col (16B chunk)

    f32x4 acc[4][4] = {};

    for (int kk = 0; kk < KCHUNK; kk += BKT) {
        __syncthreads();
        // stage A 128x32: f32 load -> f16 round -> LDS
        #pragma unroll
        for (int i = 0; i < 4; ++i) {
            const float4 v = *(const float4*)(Ab + (size_t)(am + 32 * i) * KDIM + kk + ak);
            half4v h;
            h[0] = (_Float16)v.x; h[1] = (_Float16)v.y;
            h[2] = (_Float16)v.z; h[3] = (_Float16)v.w;
            *(half4v*)&As[am + 32 * i][ak] = h;
        }
        // stage B hi/lo 128x32 f16 (already transposed: rows are n, k-contiguous)
        #pragma unroll
        for (int i = 0; i < 2; ++i) {
            const int n = bnr + 64 * i;
            *(half8*)&Bhs[n][bk] = *(const half8*)(Bhb + (size_t)n * KDIM + kk + bk);
            *(half8*)&Bls[n][bk] = *(const half8*)(Blb + (size_t)n * KDIM + kk + bk);
        }
        __syncthreads();

        const int r16 = lane & 15;
        const int k8  = (lane >> 4) * 8;
        half8 av[4], bh[4], bl[4];
        #pragma unroll
        for (int mf = 0; mf < 4; ++mf)
            av[mf] = *(const half8*)&As[wm * 64 + mf * 16 + r16][k8];
        #pragma unroll
        for (int nf = 0; nf < 4; ++nf) {
            bh[nf] = *(const half8*)&Bhs[wn * 64 + nf * 16 + r16][k8];
            bl[nf] = *(const half8*)&Bls[wn * 64 + nf * 16 + r16][k8];
        }
        #pragma unroll
        for (int mf = 0; mf < 4; ++mf)
            #pragma unroll
            for (int nf = 0; nf < 4; ++nf) {
                acc[mf][nf] = __builtin_amdgcn_mfma_f32_16x16x32_f16(av[mf], bh[nf], acc[mf][nf], 0, 0, 0);
                acc[mf][nf] = __builtin_amdgcn_mfma_f32_16x16x32_f16(av[mf], bl[nf], acc[mf][nf], 0, 0, 0);
            }
    }

    // epilogue: C/D layout col=lane&15, row=4*(lane>>4)+reg (m89-verified)
    const int row0 = bm * BMT + wm * 64 + (lane >> 4) * 4;
    const int col0 = bn * BNT + wn * 64 + (lane & 15);
    #pragma unroll
    for (int mf = 0; mf < 4; ++mf)
        #pragma unroll
        for (int nf = 0; nf < 4; ++nf)
            #pragma unroll
            for (int r = 0; r < 4; ++r)
                atomicAdd(&C[(size_t)(row0 + mf * 16 + r) * NCOLS + col0 + nf * 16],
                          acc[mf][nf][r]);
}

// ------------------------------------------------------------------
// Fallback vector-FMA GEMM (verified baseline) — used only if ws too small
// ------------------------------------------------------------------
__global__ __launch_bounds__(256, 2)
void gemm_splitk_kernel(const float* __restrict__ A, const float* __restrict__ B,
                        float* __restrict__ C)
{
    __shared__ float As[BK][SA];
    __shared__ float Bs[BK][SB];

    const int t  = threadIdx.x;
    const int tx = t & 15;
    const int ty = t >> 4;

    const int bm = blockIdx.x;
    const int bn = blockIdx.y;
    const int bs = blockIdx.z;

    const float* Ab = A + (size_t)bm * BM * KDIM + (size_t)bs * KCHUNK;
    const float* Bb = B + (size_t)bs * KCHUNK * NCOLS + bn * BN;

    const int arow = t >> 3;
    const int akf4 = t & 7;
    const int bkr  = t >> 5;
    const int bnf4 = t & 31;

    float acc[8][8];
    #pragma unroll
    for (int i = 0; i < 8; ++i)
        #pragma unroll
        for (int j = 0; j < 8; ++j) acc[i][j] = 0.f;

    for (int kk = 0; kk < KCHUNK; kk += BK) {
        #pragma unroll
        for (int i = 0; i < 4; ++i) {
            const int r = arow + 32 * i;
            const float4 v = *(const float4*)(Ab + (size_t)r * KDIM + kk + akf4 * 4);
            As[akf4 * 4 + 0][r] = v.x;
            As[akf4 * 4 + 1][r] = v.y;
            As[akf4 * 4 + 2][r] = v.z;
            As[akf4 * 4 + 3][r] = v.w;
        }
        #pragma unroll
        for (int i = 0; i < 4; ++i) {
            const int r = bkr + 8 * i;
            *(float4*)&Bs[r][bnf4 * 4] =
                *(const float4*)(Bb + (size_t)(kk + r) * NCOLS + bnf4 * 4);
        }
        __syncthreads();

        #pragma unroll 8
        for (int k = 0; k < BK; ++k) {
            float a[8], b[8];
            *(float4*)&a[0] = *(const float4*)&As[k][ty * 4];
            *(float4*)&a[4] = *(const float4*)&As[k][64 + ty * 4];
            *(float4*)&b[0] = *(const float4*)&Bs[k][tx * 4];
            *(float4*)&b[4] = *(const float4*)&Bs[k][64 + tx * 4];
            #pragma unroll
            for (int i = 0; i < 8; ++i)
                #pragma unroll
                for (int j = 0; j < 8; ++j)
                    acc[i][j] = fmaf(a[i], b[j], acc[i][j]);
        }
        __syncthreads();
    }

    #pragma unroll
    for (int i = 0; i < 8; ++i) {
        const int row = bm * BM + ty * 4 + (i & 3) + 64 * (i >> 2);
        #pragma unroll
        for (int j = 0; j < 8; ++j) {
            const int col = bn * BN + tx * 4 + (j & 3) + 64 * (j >> 2);
            atomicAdd(&C[(size_t)row * NCOLS + col], acc[i][j]);
        }
    }
}

// ---- fused bias + mask + student-t + argmax (unchanged, verified) ----
#define RPB 8

__global__ __launch_bounds__(256, 1)
void student_t_kernel(float* __restrict__ zbuf,
                      const int* __restrict__ mask,
                      const float* __restrict__ b_emb,
                      const float* __restrict__ cent,
                      float* __restrict__ s_out,
                      float* __restrict__ c_out)
{
    __shared__ float cs[50][257];
    __shared__ float zs[RPB][256];
    __shared__ float stbuf[RPB][128];
    __shared__ float c2[NCLU];
    __shared__ float z2s[RPB];
    __shared__ float redbuf[4];
    __shared__ float r_sum, r_idx;

    const int t    = threadIdx.x;
    const int wid  = t >> 6;
    const int lane = t & 63;
    const int row0 = blockIdx.x * RPB;

    const float bt = b_emb[t];

    if (t >= 100 && t < 128) {
        #pragma unroll
        for (int r = 0; r < RPB; ++r) stbuf[r][t] = 0.f;
    }

    for (int r = 0; r < RPB; ++r) {
        const int row = row0 + r;
        const float z = zbuf[(size_t)row * NCOLS + t] + bt;
        const bool m = mask[row] != 0;
        zbuf[(size_t)row * NCOLS + t] = m ? z : 0.f;
        zs[r][t] = z;
        float v = z * z;
        #pragma unroll
        for (int off = 32; off > 0; off >>= 1) v += __shfl_down(v, off, 64);
        if (lane == 0) redbuf[wid] = v;
        __syncthreads();
        if (t == 0) z2s[r] = redbuf[0] + redbuf[1] + redbuf[2] + redbuf[3];
        __syncthreads();
    }

    for (int ch = 0; ch < 2; ++ch) {
        const int kbase = ch * 50;
        for (int i = t; i < 50 * 256; i += 256) {
            const int k = i >> 8;
            const int d = i & 255;
            cs[k][d] = cent[(size_t)(kbase + k) * 256 + d];
        }
        __syncthreads();
        if (t < 50) {
            float s = 0.f;
            for (int d = 0; d < 256; ++d) s = fmaf(cs[t][d], cs[t][d], s);
            c2[kbase + t] = s;
        }
        __syncthreads();
        for (int rp = 0; rp < RPB / 2; ++rp) {
            if (t < 100) {
                const int r = rp * 2 + t / 50;
                const int k = t % 50;
                float dot = 0.f;
                for (int d = 0; d < 256; ++d)
                    dot = fmaf(zs[r][d], cs[k][d], dot);
                const float d2   = z2s[r] + c2[kbase + k] - 2.f * dot;
                const float dist = sqrtf(fmaxf(d2, 0.f));
                stbuf[r][kbase + k] = 1.f / (1.f + dist);
            }
        }
        __syncthreads();
    }

    for (int r = 0; r < RPB; ++r) {
        const int row = row0 + r;
        if (wid == 0) {
            const float v1 = stbuf[r][lane];
            const float v2 = stbuf[r][lane + 64];
            float sv = v1 + v2;
            #pragma unroll
            for (int off = 32; off > 0; off >>= 1) sv += __shfl_down(sv, off, 64);
            float mv; int mi;
            if (v2 > v1) { mv = v2; mi = lane + 64; } else { mv = v1; mi = lane; }
            #pragma unroll
            for (int off = 32; off > 0; off >>= 1) {
                const float ov = __shfl_down(mv, off, 64);
                const int   oi = __shfl_down(mi, off, 64);
                if (ov > mv || (ov == mv && oi < mi)) { mv = ov; mi = oi; }
            }
            if (lane == 0) { r_sum = sv; r_idx = (float)mi; }
        }
        __syncthreads();
        const bool m = mask[row] != 0;
        if (t < NCLU) s_out[(size_t)row * NCLU + t] = m ? stbuf[r][t] / r_sum : 0.f;
        if (t == 0)   c_out[row] = m ? r_idx : 0.f;
        __syncthreads();
    }
}

extern "C" void kernel_launch(void* const* d_in, const int* in_sizes, int n_in,
                              void* d_out, int out_size, void* d_ws, size_t ws_size,
                              hipStream_t stream)
{
    const float* z_roi = (const float*)d_in[0];
    const int*   mask  = (const int*)d_in[1];
    const float* w_emb = (const float*)d_in[2];
    const float* b_emb = (const float*)d_in[3];
    const float* cent  = (const float*)d_in[4];

    float* out   = (float*)d_out;
    float* z_all = out;
    float* s_out = out + (size_t)MROWS * NCOLS;
    float* c_out = s_out + (size_t)MROWS * NCLU;

    // zero the split-K accumulator region (d_out is poisoned every launch)
    hipMemsetAsync(z_all, 0, (size_t)MROWS * NCOLS * sizeof(float), stream);

    const size_t bt_elems = (size_t)NCOLS * KDIM;                    // 16.7M halves per matrix
    const size_t ws_need  = bt_elems * 2 * sizeof(_Float16);         // 64 MB (hi + lo)

    if (ws_size >= ws_need) {
        _Float16* bth = (_Float16*)d_ws;
        _Float16* btl = bth + bt_elems;
        prep_b_kernel<<<dim3(KDIM / 64, NCOLS / 64), 256, 0, stream>>>(w_emb, bth, btl);
        gemm_mfma_kernel<<<dim3(MROWS / BMT, NCOLS / BNT, SPLITK), 256, 0, stream>>>(
            z_roi, bth, btl, z_all);
    } else {
        gemm_splitk_kernel<<<dim3(MROWS / BM, NCOLS / BN, SPLITK), 256, 0, stream>>>(
            z_roi, w_emb, z_all);
    }

    student_t_kernel<<<dim3(MROWS / RPB), 256, 0, stream>>>(z_all, mask, b_emb, cent,
                                                            s_out, c_out);
}